// Round 8
// baseline (99.786 us; speedup 1.0000x reference)
//
#include <hip/hip_runtime.h>
#include <hip/hip_fp16.h>

// QDPPMixer, R8: R7 (G=4 quad gather, fp16 table, DPP reduce, normalize-free
// algebra) + 2 ELEMENTS PER THREAD for memory-level parallelism.
// R7 lesson: halving lane-requests/lines gave only ~10% -> not a TA-throughput
// wall. Revised model: latency x MLP bound (~9.6 waves/CU x 8 lines in flight
// ~= 77 outstanding lines/CU at ~450cyc L2 latency ~= the whole 29us kernel).
// R8 issues BOTH elements' 16 gathers before consuming either; element B's
// loads stay in flight across element A's entire Gram compute. Gram consumes
// rows j-outer (issue order) so the compiler can use graduated vmcnt waits.

constexpr int   NA         = 8;
constexpr float Q_MIN      = -10.0f;
constexpr float Q_MAX      = 10.0f;
constexpr float NOISE_COEF = 0.1f;
constexpr float EPS        = 1e-8f;

#define P(i, j) ((j) * ((j) + 1) / 2 + (i))   // upper-tri flat index, i<=j (j-major)

typedef _Float16 half2_t __attribute__((ext_vector_type(2)));

__device__ __forceinline__ float dot2(half2_t a, half2_t b, float c) {
#if __has_builtin(__builtin_amdgcn_fdot2)
    return __builtin_amdgcn_fdot2(a, b, c, false);
#else
    return fmaf((float)a.x, (float)b.x, fmaf((float)a.y, (float)b.y, c));
#endif
}

// quad butterfly adds (pure VALU DPP)
__device__ __forceinline__ float qadd1(float x) {
    return x + __builtin_bit_cast(float,
        __builtin_amdgcn_mov_dpp(__builtin_bit_cast(int, x), 0xB1, 0xF, 0xF, true));
}
__device__ __forceinline__ float qadd2(float x) {
    return x + __builtin_bit_cast(float,
        __builtin_amdgcn_mov_dpp(__builtin_bit_cast(int, x), 0x4E, 0xF, 0xF, true));
}

// partial Gram from 8 gathered 16B row-slices, consumed j-outer (issue order)
__device__ __forceinline__ void gram_from_raw(const uint4 raw[8], float g[36]) {
    half2_t h[8][4];
    #pragma unroll
    for (int j = 0; j < 8; j++) {
        h[j][0] = __builtin_bit_cast(half2_t, raw[j].x);
        h[j][1] = __builtin_bit_cast(half2_t, raw[j].y);
        h[j][2] = __builtin_bit_cast(half2_t, raw[j].z);
        h[j][3] = __builtin_bit_cast(half2_t, raw[j].w);
        #pragma unroll
        for (int i = 0; i <= j; i++) {
            float acc = dot2(h[i][0], h[j][0], 0.0f);
            acc = dot2(h[i][1], h[j][1], acc);
            acc = dot2(h[i][2], h[j][2], acc);
            acc = dot2(h[i][3], h[j][3], acc);
            g[P(i, j)] = acc;
        }
    }
}

// epilogue: butterfly-reduce g across quad, build Atil, LU, return out value
__device__ __forceinline__ float epilogue(float g[36],
                                          float4 qa, float4 qb,
                                          float4 n0, float4 n1) {
    #pragma unroll
    for (int k = 0; k < 36; k++)
        g[k] = qadd2(qadd1(g[k]));

    float qsum = fminf(fmaxf(qa.x, Q_MIN), Q_MAX) + fminf(fmaxf(qa.y, Q_MIN), Q_MAX)
               + fminf(fmaxf(qa.z, Q_MIN), Q_MAX) + fminf(fmaxf(qa.w, Q_MIN), Q_MAX)
               + fminf(fmaxf(qb.x, Q_MIN), Q_MAX) + fminf(fmaxf(qb.y, Q_MIN), Q_MAX)
               + fminf(fmaxf(qb.z, Q_MIN), Q_MAX) + fminf(fmaxf(qb.w, Q_MIN), Q_MAX);

    float nz[8] = {n0.x, n0.y, n0.z, n0.w, n1.x, n1.y, n1.z, n1.w};

    // Atil: off-diag = relu(g_ij), diag = g_ii*(1 + 0.1*nz_i + eps)
    float m[8][8];
    float pgii = 1.0f;
    #pragma unroll
    for (int i = 0; i < 8; i++) {
        float gii = g[P(i, i)];
        pgii *= gii;
        m[i][i] = gii * fmaf(NOISE_COEF, nz[i], 1.0f + EPS);
        #pragma unroll
        for (int j = i + 1; j < 8; j++) {
            float r = fmaxf(g[P(i, j)], 0.0f);
            m[i][j] = r;
            m[j][i] = r;
        }
    }

    // det via unrolled no-pivot LU (diag-dominant in practice)
    float det = 1.0f;
    #pragma unroll
    for (int k = 0; k < 8; k++) {
        float p = m[k][k];
        det *= p;
        float ip = __builtin_amdgcn_rcpf(p);
        #pragma unroll
        for (int i = k + 1; i < 8; i++) {
            float f = m[i][k] * ip;
            #pragma unroll
            for (int j = k + 1; j < 8; j++)
                m[i][j] = fmaf(-f, m[k][j], m[i][j]);
        }
    }

    float detM = det * __builtin_amdgcn_rcpf(pgii);
    return qsum + __logf(detM + EPS);
}

// ---- convert W (8000x32 fp32) -> fp16, 4 floats/thread ----
__global__ __launch_bounds__(256) void convert_kernel(
    const float* __restrict__ W, __half* __restrict__ W16, int n4)
{
    int t = blockIdx.x * blockDim.x + threadIdx.x;
    if (t >= n4) return;
    float4 v = reinterpret_cast<const float4*>(W)[t];
    ushort4 h;
    h.x = __half_as_ushort(__float2half(v.x));
    h.y = __half_as_ushort(__float2half(v.y));
    h.z = __half_as_ushort(__float2half(v.z));
    h.w = __half_as_ushort(__float2half(v.w));
    reinterpret_cast<ushort4*>(W16)[t] = h;
}

__device__ __forceinline__ void make_off(int4 s0, int4 s1, int4 a0, int4 a1,
                                         int lb, int off[8]) {
    off[0] = (s0.x * 10 + a0.x        ) * 32 + lb;
    off[1] = (s0.y * 10 + a0.y + 1000 ) * 32 + lb;
    off[2] = (s0.z * 10 + a0.z + 2000 ) * 32 + lb;
    off[3] = (s0.w * 10 + a0.w + 3000 ) * 32 + lb;
    off[4] = (s1.x * 10 + a1.x + 4000 ) * 32 + lb;
    off[5] = (s1.y * 10 + a1.y + 5000 ) * 32 + lb;
    off[6] = (s1.z * 10 + a1.z + 6000 ) * 32 + lb;
    off[7] = (s1.w * 10 + a1.w + 7000 ) * 32 + lb;
}

__global__ __launch_bounds__(256, 4) void qdpp_kernel(
    const float* __restrict__ agent_qs,
    const int*   __restrict__ states,
    const int*   __restrict__ actions,
    const float* __restrict__ noise,
    const __half* __restrict__ W16,   // (8000, 32) fp16, rows 64B
    float*       __restrict__ out,
    int bs)
{
    int tid = blockIdx.x * blockDim.x + threadIdx.x;
    int q = tid >> 2;          // quad id
    int l = tid & 3;           // lane in quad: halves [8l, 8l+8) of each row
    int half_bs = bs >> 1;
    if (q >= half_bs) return;
    int eA = q;
    int eB = q + half_bs;
    size_t baseA = (size_t)eA * NA;
    size_t baseB = (size_t)eB * NA;
    int lb = 8 * l;

    // ---- element A indices + gathers (8 loads) ----
    int offA[8];
    {
        int4 s0 = *reinterpret_cast<const int4*>(states + baseA);
        int4 s1 = *reinterpret_cast<const int4*>(states + baseA + 4);
        int4 a0 = *reinterpret_cast<const int4*>(actions + baseA);
        int4 a1 = *reinterpret_cast<const int4*>(actions + baseA + 4);
        make_off(s0, s1, a0, a1, lb, offA);
    }
    uint4 rawA[8];
    #pragma unroll
    for (int i = 0; i < 8; i++)
        rawA[i] = *reinterpret_cast<const uint4*>(W16 + offA[i]);

    // ---- element B indices + gathers (8 more loads; 16 in flight) ----
    int offB[8];
    {
        int4 s0 = *reinterpret_cast<const int4*>(states + baseB);
        int4 s1 = *reinterpret_cast<const int4*>(states + baseB + 4);
        int4 a0 = *reinterpret_cast<const int4*>(actions + baseB);
        int4 a1 = *reinterpret_cast<const int4*>(actions + baseB + 4);
        make_off(s0, s1, a0, a1, lb, offB);
    }
    uint4 rawB[8];
    #pragma unroll
    for (int i = 0; i < 8; i++)
        rawB[i] = *reinterpret_cast<const uint4*>(W16 + offB[i]);

    // ---- element A: stream loads + Gram (B's gathers remain in flight) ----
    float4 qa_A = *reinterpret_cast<const float4*>(agent_qs + baseA);
    float4 qb_A = *reinterpret_cast<const float4*>(agent_qs + baseA + 4);
    float4 n0_A = *reinterpret_cast<const float4*>(noise + baseA);
    float4 n1_A = *reinterpret_cast<const float4*>(noise + baseA + 4);

    float gA[36];
    gram_from_raw(rawA, gA);
    float outA = epilogue(gA, qa_A, qb_A, n0_A, n1_A);
    if (l == 0) out[eA] = outA;

    // ---- element B ----
    float4 qa_B = *reinterpret_cast<const float4*>(agent_qs + baseB);
    float4 qb_B = *reinterpret_cast<const float4*>(agent_qs + baseB + 4);
    float4 n0_B = *reinterpret_cast<const float4*>(noise + baseB);
    float4 n1_B = *reinterpret_cast<const float4*>(noise + baseB + 4);

    float gB[36];
    gram_from_raw(rawB, gB);
    float outB = epilogue(gB, qa_B, qb_B, n0_B, n1_B);
    if (l == 0) out[eB] = outB;
}

extern "C" void kernel_launch(void* const* d_in, const int* in_sizes, int n_in,
                              void* d_out, int out_size, void* d_ws, size_t ws_size,
                              hipStream_t stream) {
    const float* agent_qs = (const float*)d_in[0];
    const int*   states   = (const int*)d_in[1];
    const int*   actions  = (const int*)d_in[2];
    const float* noise    = (const float*)d_in[3];
    const float* W        = (const float*)d_in[4];
    float*       out      = (float*)d_out;
    __half*      W16      = (__half*)d_ws;          // 256000 halves = 512 KB

    int wn = in_sizes[4];             // 256000 floats
    int n4 = wn / 4;
    convert_kernel<<<(n4 + 255) / 256, 256, 0, stream>>>(W, W16, n4);

    int bs = in_sizes[0] / NA;            // 262144
    const int block = 256;
    long long total = (long long)(bs / 2) * 4;  // 2 elements per thread, 4 lanes/elem
    int grid = (int)((total + block - 1) / block);
    qdpp_kernel<<<grid, block, 0, stream>>>(agent_qs, states, actions, noise, W16, out, bs);
}